// Round 3
// baseline (21.008 us; speedup 1.0000x reference)
//
#include <hip/hip_runtime.h>

// upsample_nn: values [C=64, N=4096] f32, coords [N,2] f32 in [0,1)
// out [C, 4N]: first N cols = values, next 3N cols = values[:, argmin_j d2(g,j)]
// Reference (numpy/jax f32, faithful replication — contraction DISABLED):
//   q built in f32:  qx = (x [+0.001f]) - 0.0005f, qy likewise
//   qq = qx*qx + qy*qy            (plain mul, mul, add — no fma)
//   cc = cx*cx + cy*cy            (plain)
//   qc = fmaf(qy, cy, qx*cx)      (BLAS/Eigen K=2 sgemm: ascending-k FMA from 0)
//   d2 = (qq + cc) - (qc + qc)    (left-assoc; 2*qc exact)
//   argmin = first occurrence (strict <, ascending j, idx tie-break on merges)

#pragma clang fp contract(off)

constexpr int Nn     = 4096;
constexpr int Cc     = 64;
constexpr int QPB    = 16;              // queries per block
constexpr int NCHUNK = 16;              // candidate chunks, stride-16 interleaved
constexpr int CHUNK  = Nn / NCHUNK;     // 256 candidates per thread
constexpr int NQ     = 3 * Nn;          // 12288 new queries
constexpr int NBLK   = NQ / QPB;        // 768 blocks

__global__ __launch_bounds__(256) void upsample_nn_kernel(
    const float* __restrict__ values,   // [Cc][Nn]
    const float* __restrict__ coords,   // [Nn][2]
    float* __restrict__ out)            // [Cc][4*Nn]
{
#pragma clang fp contract(off)
    __shared__ float2 sC[Nn];           // 32 KB: candidate coords
    __shared__ float  sCC[Nn];          // 16 KB: candidate |c|^2 (plain rounding)
    __shared__ float  pD[NCHUNK][QPB];
    __shared__ int    pI[NCHUNK][QPB];
    __shared__ int    sIdx[QPB];

    const int tid = threadIdx.x;

    // ---- stage coords + squared norms into LDS (coalesced float2 loads) ----
    #pragma unroll
    for (int k = 0; k < Nn / 256; ++k) {
        int j = tid + k * 256;
        float2 c = reinterpret_cast<const float2*>(coords)[j];
        sC[j] = c;
        sCC[j] = c.x * c.x + c.y * c.y;           // contract(off): mul,mul,add
    }

    // ---- copy values -> out[:, 0:N] as float4 (fused, independent work) ----
    {
        int gtid = blockIdx.x * 256 + tid;
        if (gtid < Cc * (Nn / 4)) {
            int row = gtid >> 10;                 // Nn/4 = 1024 float4 per values row
            int c4  = gtid & 1023;
            float4 v = reinterpret_cast<const float4*>(values)[row * (Nn / 4) + c4];
            reinterpret_cast<float4*>(out)[row * Nn + c4] = v;  // out row = Nn float4
        }
    }

    // ---- per-thread query setup (f32, faithful rounding) ----
    const int q    = tid & (QPB - 1);             // query slot in block
    const int chk  = tid >> 4;                    // candidate chunk [0,16)
    const int g    = blockIdx.x * QPB + q;        // global new-query id [0, 3N)
    const int i    = g & (Nn - 1);                // source point index
    const int var  = g >> 12;                     // variant 0/1/2

    float2 ci = reinterpret_cast<const float2*>(coords)[i];
    const float x = ci.x, y = ci.y;
    float qx, qy;
    if (var == 0) {                               // (x, y+sy) - shift
        qx = x - 0.0005f;
        qy = (y + 0.001f) - 0.0005f;
    } else if (var == 1) {                        // (x+sx, y) - shift
        qx = (x + 0.001f) - 0.0005f;
        qy = y - 0.0005f;
    } else {                                      // (x+sx, y+sy) - shift
        qx = (x + 0.001f) - 0.0005f;
        qy = (y + 0.001f) - 0.0005f;
    }
    const float qq = qx * qx + qy * qy;           // contract(off): plain

    __syncthreads();

    // ---- scan this thread's candidates: j = chk + 16*t, t in [0,256) ----
    // (stride-16 so the 4 chunk-groups of a wave hit distinct LDS banks;
    //  first-occurrence preserved via (d2, idx) tie-breaks at every merge)
    float bd0 = INFINITY, bd1 = INFINITY, bd2 = INFINITY, bd3 = INFINITY;
    int   bi0 = 0x7fffffff, bi1 = 0x7fffffff, bi2 = 0x7fffffff, bi3 = 0x7fffffff;

#define CAND(JJ, BD, BI)                                                      \
    {                                                                         \
        int    jj = (JJ);                                                     \
        float2 c  = sC[jj];                                                   \
        float  cc = sCC[jj];                                                  \
        float  qc = __builtin_fmaf(qy, c.y, qx * c.x);                        \
        float  d2 = (qq + cc) - (qc + qc);                                    \
        if (d2 < (BD)) { (BD) = d2; (BI) = jj; }                              \
    }

    for (int t = 0; t < CHUNK; t += 4) {
        CAND(chk + 16 * (t + 0), bd0, bi0);
        CAND(chk + 16 * (t + 1), bd1, bi1);
        CAND(chk + 16 * (t + 2), bd2, bi2);
        CAND(chk + 16 * (t + 3), bd3, bi3);
    }
#undef CAND

    // merge accumulators; equal d2 -> smaller index (first occurrence)
#define MERGE(BD, BI, D, I)                                                   \
    {                                                                         \
        bool take = ((D) < (BD)) || (((D) == (BD)) && ((I) < (BI)));          \
        if (take) { (BD) = (D); (BI) = (I); }                                 \
    }
    MERGE(bd0, bi0, bd1, bi1);
    MERGE(bd0, bi0, bd2, bi2);
    MERGE(bd0, bi0, bd3, bi3);

    pD[chk][q] = bd0;
    pI[chk][q] = bi0;
    __syncthreads();

    // ---- cross-chunk reduce with idx tie-break ----
    if (tid < QPB) {
        float bd = pD[0][tid];
        int   bi = pI[0][tid];
        #pragma unroll
        for (int c = 1; c < NCHUNK; ++c) {
            float d  = pD[c][tid];
            int   i2 = pI[c][tid];
            MERGE(bd, bi, d, i2);
        }
        sIdx[tid] = bi;
    }
#undef MERGE
    __syncthreads();

    // ---- gather epilogue: out[ch, N + g] = values[ch, idx] ----
    const int gbase = blockIdx.x * QPB;
    #pragma unroll
    for (int it = 0; it < 4; ++it) {
        int chn = (tid >> 4) + it * 16;
        int ql  = tid & 15;
        int id  = sIdx[ql];
        out[(size_t)chn * (4 * Nn) + Nn + gbase + ql] = values[chn * Nn + id];
    }
}

extern "C" void kernel_launch(void* const* d_in, const int* in_sizes, int n_in,
                              void* d_out, int out_size, void* d_ws, size_t ws_size,
                              hipStream_t stream) {
    const float* values = (const float*)d_in[0];  // [64, 4096] f32
    const float* coords = (const float*)d_in[1];  // [4096, 2] f32
    float* out = (float*)d_out;                   // [64, 16384] f32
    hipLaunchKernelGGL(upsample_nn_kernel, dim3(NBLK), dim3(256), 0, stream,
                       values, coords, out);
}